// Round 6
// baseline (253.017 us; speedup 1.0000x reference)
//
#include <hip/hip_runtime.h>

typedef unsigned short u16;
typedef unsigned char  u8;
typedef unsigned long long u64;
typedef __attribute__((ext_vector_type(8))) short bf16x8;   // 8 bf16 in 4 VGPRs
typedef __attribute__((ext_vector_type(4))) float f32x4;

constexpr int B_  = 2;
constexpr int S_  = 2048;
constexpr int D_  = 1024;
constexpr int H_  = 16;
constexpr int DK_ = 64;
constexpr int NROW = B_ * S_;                           // 4096
constexpr size_t QSZ  = (size_t)B_ * H_ * S_ * DK_;     // 4194304 elems per buffer
constexpr size_t XBSZ = (size_t)NROW * D_;              // 4194304 (one X matrix)
constexpr size_t WBSZ = (size_t)D_ * D_;                // 1048576 (one W matrix)
constexpr size_t MSZ  = (size_t)B_ * S_ * S_;           // 8388608 mask elems
constexpr size_t MPKB = MSZ / 8;                        // 1 MiB packed mask bytes

__device__ __forceinline__ u16 f2bf(float f) {
    union { float f; unsigned u; } c; c.f = f;
    unsigned r = c.u + 0x7fffu + ((c.u >> 16) & 1u);    // RNE
    return (u16)(r >> 16);
}
__device__ __forceinline__ unsigned pack2(float a, float b) {
    return (unsigned)f2bf(a) | ((unsigned)f2bf(b) << 16);
}
// HW packed f32->bf16 RNE: bit-identical to f2bf for finite values.
__device__ __forceinline__ unsigned cvt_pk_bf16(float a, float b) {
    unsigned r;
    asm("v_cvt_pk_bf16_f32 %0, %1, %2" : "=v"(r) : "v"(a), "v"(b));
    return r;
}

// async global->LDS, 16B per lane; lds ptr must be wave-uniform base
__device__ __forceinline__ void gl_lds16(const u16* g, u16* l) {
    __builtin_amdgcn_global_load_lds(
        (const __attribute__((address_space(1))) void*)g,
        (__attribute__((address_space(3))) void*)l, 16, 0, 0);
}

// ---------------------------------------------------------------------------
// cvt7m — UNCHANGED from R11. fp32 -> bf16 RNE of X/W + mask bit-pack.
// ---------------------------------------------------------------------------
__global__ __launch_bounds__(256)
void cvt7m(const float* __restrict__ s0, const float* __restrict__ s1,
           const float* __restrict__ s2, const float* __restrict__ s3,
           const float* __restrict__ s4, const float* __restrict__ s5,
           const float* __restrict__ s6, const int* __restrict__ mk,
           u16* __restrict__ d0, u16* __restrict__ d1, u16* __restrict__ d2,
           u16* __restrict__ d3, u16* __restrict__ d4, u16* __restrict__ d5,
           u16* __restrict__ d6, u8* __restrict__ mp)
{
    constexpr size_t XT = 3 * XBSZ;                            // 12582912
    constexpr int NCF = (int)((3 * XBSZ + 4 * WBSZ) / 2048);   // 8192
    constexpr int NCM = (int)(MSZ / 2048);                     // 4096

    for (int c = blockIdx.x; c < NCF + NCM; c += gridDim.x) {
        if (c < NCF) {
            const size_t base = (size_t)c * 2048;
            const float* s; u16* d; size_t off;
            if (base < XT) {
                const int a = (int)(base >> 22);
                off = base & (XBSZ - 1);
                s = (a == 0) ? s0 : (a == 1) ? s1 : s2;
                d = (a == 0) ? d0 : (a == 1) ? d1 : d2;
            } else {
                const size_t r = base - XT;
                const int a = (int)(r >> 20);
                off = r & (WBSZ - 1);
                s = (a == 0) ? s3 : (a == 1) ? s4 : (a == 2) ? s5 : s6;
                d = (a == 0) ? d3 : (a == 1) ? d4 : (a == 2) ? d5 : d6;
            }
            const size_t e = off + (size_t)threadIdx.x * 8;
            const float4 x0 = *(const float4*)(s + e);
            const float4 x1 = *(const float4*)(s + e + 4);
            uint4 p;
            p.x = pack2(x0.x, x0.y); p.y = pack2(x0.z, x0.w);
            p.z = pack2(x1.x, x1.y); p.w = pack2(x1.z, x1.w);
            *(uint4*)(d + e) = p;
        } else {
            const size_t e = (size_t)(c - NCF) * 2048 + (size_t)threadIdx.x * 8;
            const int4 x0 = *(const int4*)(mk + e);
            const int4 x1 = *(const int4*)(mk + e + 4);
            unsigned bv = (unsigned)(x0.x != 0)        | ((unsigned)(x0.y != 0) << 1)
                        | ((unsigned)(x0.z != 0) << 2) | ((unsigned)(x0.w != 0) << 3)
                        | ((unsigned)(x1.x != 0) << 4) | ((unsigned)(x1.y != 0) << 5)
                        | ((unsigned)(x1.z != 0) << 6) | ((unsigned)(x1.w != 0) << 7);
            mp[e >> 3] = (u8)bv;
        }
    }
}

// ---------------------------------------------------------------------------
// qkv_gemm — UNCHANGED from R14 (BK=64 stacked half-tiles).
// ---------------------------------------------------------------------------
__global__ __launch_bounds__(256, 3)
void qkv_gemm(const u16* __restrict__ Xq, const u16* __restrict__ Xk,
              const u16* __restrict__ Xv,
              const u16* __restrict__ Wq, const u16* __restrict__ Wk,
              const u16* __restrict__ Wv,
              u16* __restrict__ Yq, u16* __restrict__ Yk, u16* __restrict__ Yv)
{
    __shared__ u16 As[2 * 128 * 32];    // [kk][row][col]
    __shared__ u16 Bs[2 * 128 * 32];

    const int z = blockIdx.z;
    const u16* X = (z == 0) ? Xq : (z == 1) ? Xk : Xv;
    const u16* W = (z == 0) ? Wq : (z == 1) ? Wk : Wv;
    u16*       Y = (z == 0) ? Yq : (z == 1) ? Yk : Yv;
    const float osc = (z == 0) ? 0.125f : 1.0f;

    const int tid  = threadIdx.x;
    const int lane = tid & 63;
    const int w    = tid >> 6;
    const int quad = lane >> 4;
    const int lq   = lane & 15;
    const int wm   = (w & 1) << 6;
    const int wn   = (w >> 1) << 6;

    const int m0 = blockIdx.x << 7;
    const int n0 = blockIdx.y << 7;

    const int srow = tid >> 2;
    const int scol = (tid & 3) << 3;
    const u16* ga0 = X + (size_t)(m0 + srow) * D_ + scol;
    const u16* ga1 = ga0 + (size_t)64 * D_;
    const u16* gb0 = W + (size_t)(n0 + srow) * D_ + scol;
    const u16* gb1 = gb0 + (size_t)64 * D_;

    u16* la0 = As + (size_t)w * 512;
    u16* la1 = As + 2048 + (size_t)w * 512;
    u16* lb0 = Bs + (size_t)w * 512;
    u16* lb1 = Bs + 2048 + (size_t)w * 512;

    f32x4 acc[4][4];
#pragma unroll
    for (int i = 0; i < 4; ++i)
#pragma unroll
        for (int j = 0; j < 4; ++j) acc[i][j] = (f32x4){0.f, 0.f, 0.f, 0.f};

    for (int kt = 0; kt < D_; kt += 64) {
        __syncthreads();
        gl_lds16(ga0 + kt, la0);
        gl_lds16(ga1 + kt, la1);
        gl_lds16(gb0 + kt, lb0);
        gl_lds16(gb1 + kt, lb1);
        gl_lds16(ga0 + kt + 32, la0 + 4096);
        gl_lds16(ga1 + kt + 32, la1 + 4096);
        gl_lds16(gb0 + kt + 32, lb0 + 4096);
        gl_lds16(gb1 + kt + 32, lb1 + 4096);
        __syncthreads();

#pragma unroll
        for (int kk = 0; kk < 2; ++kk) {
            bf16x8 af[4], bf[4];
#pragma unroll
            for (int t = 0; t < 4; ++t) {
                af[t] = *(const bf16x8*)&As[(kk << 12) + (size_t)(wm + (t << 4) + lq) * 32 + (quad << 3)];
                bf[t] = *(const bf16x8*)&Bs[(kk << 12) + (size_t)(wn + (t << 4) + lq) * 32 + (quad << 3)];
            }
#pragma unroll
            for (int i = 0; i < 4; ++i)
#pragma unroll
                for (int j = 0; j < 4; ++j)
                    acc[i][j] = __builtin_amdgcn_mfma_f32_16x16x32_bf16(
                        af[i], bf[j], acc[i][j], 0, 0, 0);
        }
    }

#pragma unroll
    for (int i = 0; i < 4; ++i)
#pragma unroll
        for (int j = 0; j < 4; ++j)
#pragma unroll
            for (int r = 0; r < 4; ++r) {
                const int grow = m0 + wm + (i << 4) + (quad << 2) + r;
                const int of   = n0 + wn + (j << 4) + lq;
                const int b = grow >> 11, s = grow & (S_ - 1);
                const int h = of >> 6,    dk = of & 63;
                Y[(((size_t)(b * H_ + h)) * S_ + s) * DK_ + dk] =
                    f2bf(acc[i][j][r] * osc);
            }
}

// ---------------------------------------------------------------------------
// out_gemm — UNCHANGED from R14 (64x64 tile, BK=64).
// ---------------------------------------------------------------------------
__global__ __launch_bounds__(256, 4)
void out_gemm(const u16* __restrict__ X, const u16* __restrict__ W,
              float* __restrict__ Y)
{
    __shared__ u16 As[2 * 64 * 32];
    __shared__ u16 Bs[2 * 64 * 32];

    const int tid  = threadIdx.x;
    const int lane = tid & 63;
    const int w    = tid >> 6;
    const int quad = lane >> 4;
    const int lq   = lane & 15;
    const int wm   = (w & 1) << 5;
    const int wn   = (w >> 1) << 5;

    const int m0 = blockIdx.x << 6;
    const int n0 = blockIdx.y << 6;

    const int srow = tid >> 2;          // 0..63
    const int scol = (tid & 3) << 3;
    const u16* ga0 = X + (size_t)(m0 + srow) * D_ + scol;
    const u16* gb0 = W + (size_t)(n0 + srow) * D_ + scol;

    u16* la0 = As + (size_t)w * 512;
    u16* lb0 = Bs + (size_t)w * 512;

    f32x4 acc[2][2];
#pragma unroll
    for (int i = 0; i < 2; ++i)
#pragma unroll
        for (int j = 0; j < 2; ++j) acc[i][j] = (f32x4){0.f, 0.f, 0.f, 0.f};

    for (int kt = 0; kt < D_; kt += 64) {
        __syncthreads();
        gl_lds16(ga0 + kt, la0);
        gl_lds16(gb0 + kt, lb0);
        gl_lds16(ga0 + kt + 32, la0 + 2048);
        gl_lds16(gb0 + kt + 32, lb0 + 2048);
        __syncthreads();

#pragma unroll
        for (int kk = 0; kk < 2; ++kk) {
            bf16x8 af[2], bf[2];
#pragma unroll
            for (int t = 0; t < 2; ++t) {
                af[t] = *(const bf16x8*)&As[(kk << 11) + (size_t)(wm + (t << 4) + lq) * 32 + (quad << 3)];
                bf[t] = *(const bf16x8*)&Bs[(kk << 11) + (size_t)(wn + (t << 4) + lq) * 32 + (quad << 3)];
            }
#pragma unroll
            for (int i = 0; i < 2; ++i)
#pragma unroll
                for (int j = 0; j < 2; ++j)
                    acc[i][j] = __builtin_amdgcn_mfma_f32_16x16x32_bf16(
                        af[i], bf[j], acc[i][j], 0, 0, 0);
        }
    }

#pragma unroll
    for (int i = 0; i < 2; ++i)
#pragma unroll
        for (int j = 0; j < 2; ++j)
#pragma unroll
            for (int r = 0; r < 4; ++r) {
                const int grow = m0 + wm + (i << 4) + (quad << 2) + r;
                const int gcol = n0 + wn + (j << 4) + lq;
                Y[(size_t)grow * D_ + gcol] = acc[i][j][r];
            }
}

// ---------------------------------------------------------------------------
// attn_mfma9 (R15): 512 thr / 8 waves on one 128-row Q tile; wave owns 16
// q-rows (mfma7's proven low-VGPR per-thread shape -> no spill at the
// (512,4) 128-VGPR cap, unlike R12's 32-row+K-split shape). Single shared
// K/V staging per chunk: waves 0-3 stage K (R14 2-way-free map), waves 4-7
// stage V (R14 pair map) -> per-thread staging halves, total unchanged.
// 16 waves/CU = 4/SIMD (2x R11/R14). Q frags direct from global. Per-q-row
// math & order unchanged -> bit-identical. + mask prefetch, setprio(1)
// around MFMA clusters (m191: attn-positive), XCD swizzle kept.
// ---------------------------------------------------------------------------
constexpr int AP = 72;

__global__ __launch_bounds__(512, 4)
void attn_mfma9(const u16* __restrict__ qb, const u16* __restrict__ kb,
                const u16* __restrict__ vb, const u8* __restrict__ mpk,
                u16* __restrict__ ctx)
{
    __shared__ __align__(16) u16 Ks[64][AP];
    __shared__ __align__(16) u16 Vt[64][AP];     // [d][pi(key)]
    __shared__ __align__(16) u16 Ps[128][AP];    // [q][pi(key)]

    const int tid  = threadIdx.x;          // 0..511
    const int lane = tid & 63;
    const int w    = tid >> 6;             // 0..7
    const int quad = lane >> 4;
    const int lq   = lane & 15;
    const int w16  = w << 4;               // wave's 16-row base

    // bijective XCD swizzle: XCD (bid&7) gets 64 contiguous logical tiles =
    // 4 (b,h) pairs -> K/V (2 MB) resident in that XCD's L2 (R14: FETCH 70->14MB).
    const int bid = (int)(blockIdx.x + gridDim.x * (blockIdx.y + gridDim.y * blockIdx.z));
    const int swz = (bid & 7) * 64 + (bid >> 3);        // nwg = 512
    const int q0 = (swz & 15) << 7;
    const int h  = (swz >> 4) & 15;
    const int b  = swz >> 8;

    const u16* qbh = qb + (((size_t)b * H_ + h) * S_ + q0) * DK_;
    const u16* kbh = kb + ((size_t)b * H_ + h) * S_ * DK_;
    const u16* vbh = vb + ((size_t)b * H_ + h) * S_ * DK_;

    // Q fragments straight from global (one-time, L2/L3-resident)
    bf16x8 aQ0, aQ1;
    {
        const size_t qr = (size_t)(w16 + lq) * DK_;
        aQ0 = *(const bf16x8*)&qbh[qr + (quad << 3)];
        aQ1 = *(const bf16x8*)&qbh[qr + 32 + (quad << 3)];
    }

    f32x4 O[4];
    float lsum[4];
#pragma unroll
    for (int t = 0; t < 4; ++t) O[t] = (f32x4){0.f, 0.f, 0.f, 0.f};
#pragma unroll
    for (int r = 0; r < 4; ++r) lsum[r] = 0.f;

    // staging maps: waves 0-3 stage K (tid 0..255, R14 map);
    // waves 4-7 stage V (tid-256, R14 pair map).
    const int ksr = tid >> 2, ksc = (tid & 3) << 4;      // valid for tid<256
    const int t2  = tid - 256;
    const int vc  = t2 & 15;
    const int vs  = (t2 >> 4) & 1;
    const int vk0 = vc + (vs << 5);                      // keys vk0, vk0+16
    const int vdg = t2 >> 5;                             // 0..7 (8 d's)
    const int vcol = (vc << 2) + (vs << 1);              // pi(vk0); +1 = pi(vk0+16)

    uint4 kr0, kr1, vr0, vr1;
    if (w < 4) {
        kr0 = *(const uint4*)&kbh[(size_t)ksr * DK_ + ksc];
        kr1 = *(const uint4*)&kbh[(size_t)ksr * DK_ + ksc + 8];
    } else {
        vr0 = *(const uint4*)&vbh[(size_t)vk0 * DK_ + (vdg << 3)];
        vr1 = *(const uint4*)&vbh[(size_t)(vk0 + 16) * DK_ + (vdg << 3)];
    }

    const int qrow0 = q0 + w16 + (quad << 2);
    const u8* mrow = mpk + (size_t)b * S_ * (S_ / 8) + (size_t)qrow0 * (S_ / 8);

    // mask words for chunk 0
    u64 mw[4], mwn[4];
#pragma unroll
    for (int r = 0; r < 4; ++r)
        mw[r] = *(const u64*)&mrow[(size_t)r * (S_ / 8)];

    for (int k0 = 0; k0 < S_; k0 += 64) {
        __syncthreads();
        if (w < 4) {   // staged regs -> LDS (K)
            *(uint4*)&Ks[ksr][ksc]     = kr0;
            *(uint4*)&Ks[ksr][ksc + 8] = kr1;
        } else {       // staged regs -> LDS (V, conflict-free pair map)
            const u16* a0 = (const u16*)&vr0;
            const u16* a1 = (const u16*)&vr1;
#pragma unroll
            for (int i = 0; i < 8; ++i)
                *(ushort2*)&Vt[(vdg << 3) + i][vcol] = (ushort2){a0[i], a1[i]};
        }
        __syncthreads();

        if (k0 + 64 < S_) {   // prefetch next chunk (K/V + mask)
            if (w < 4) {
                const size_t kb0 = (size_t)(k0 + 64 + ksr) * DK_ + ksc;
                kr0 = *(const uint4*)&kbh[kb0];
                kr1 = *(const uint4*)&kbh[kb0 + 8];
            } else {
                const size_t vb0 = (size_t)(k0 + 64 + vk0) * DK_ + (vdg << 3);
                vr0 = *(const uint4*)&vbh[vb0];
                vr1 = *(const uint4*)&vbh[vb0 + (size_t)16 * DK_];
            }
#pragma unroll
            for (int r = 0; r < 4; ++r)
                mwn[r] = *(const u64*)&mrow[(size_t)r * (S_ / 8) + ((k0 + 64) >> 3)];
        }

        // ---- S = Q K^T ----
        f32x4 st[4];
        __builtin_amdgcn_s_setprio(1);
#pragma unroll
        for (int t = 0; t < 4; ++t) {
            const bf16x8 b0 = *(const bf16x8*)&Ks[(t << 4) + lq][quad << 3];
            const bf16x8 b1 = *(const bf16x8*)&Ks[(t << 4) + lq][32 + (quad << 3)];
            f32x4 c = {0.f, 0.f, 0.f, 0.f};
            c = __builtin_amdgcn_mfma_f32_16x16x32_bf16(aQ0, b0, c, 0, 0, 0);
            c = __builtin_amdgcn_mfma_f32_16x16x32_bf16(aQ1, b1, c, 0, 0, 0);
            st[t] = c;
        }
        __builtin_amdgcn_s_setprio(0);

        // ---- exp (fixed base; scale pre-folded), l partials, P pack ----
#pragma unroll
        for (int r = 0; r < 4; ++r) {
            const unsigned lo = (unsigned)mw[r];
            const unsigned hi = (unsigned)(mw[r] >> 32);
            float p0 = __expf(st[0][r]);
            float p1 = __expf(st[1][r]);
            float p2 = __expf(st[2][r]);
            float p3 = __expf(st[3][r]);
            p0 = ((lo >> lq) & 1u) ? p0 : 1.0f;          // key = k0 + 0*16 + lq
            p1 = ((lo >> (lq + 16)) & 1u) ? p1 : 1.0f;   // key = k0 + 1*16 + lq
            p2 = ((hi >> lq) & 1u) ? p2 : 1.0f;          // key = k0 + 2*16 + lq
            p3 = ((hi >> (lq + 16)) & 1u) ? p3 : 1.0f;   // key = k0 + 3*16 + lq
            lsum[r] += (p0 + p1) + (p2 + p3);
            uint2 pw;
            pw.x = cvt_pk_bf16(p0, p1);
            pw.y = cvt_pk_bf16(p2, p3);
            *(uint2*)&Ps[w16 + (quad << 2) + r][lq << 2] = pw;
        }

        // ---- O += P V (wave-local Ps rows: DS in-order, no barrier) ----
        bf16x8 aP0, aP1;
        aP0 = *(const bf16x8*)&Ps[w16 + lq][quad << 3];
        aP1 = *(const bf16x8*)&Ps[w16 + lq][32 + (quad << 3)];
        __builtin_amdgcn_s_setprio(1);
#pragma unroll
        for (int t = 0; t < 4; ++t) {
            const bf16x8 b0 = *(const bf16x8*)&Vt[(t << 4) + lq][quad << 3];
            const bf16x8 b1 = *(const bf16x8*)&Vt[(t << 4) + lq][32 + (quad << 3)];
            O[t] = __builtin_amdgcn_mfma_f32_16x16x32_bf16(aP0, b0, O[t], 0, 0, 0);
            O[t] = __builtin_amdgcn_mfma_f32_16x16x32_bf16(aP1, b1, O[t], 0, 0, 0);
        }
        __builtin_amdgcn_s_setprio(0);

        if (k0 + 64 < S_) {
#pragma unroll
            for (int r = 0; r < 4; ++r) mw[r] = mwn[r];
        }
    }

    // deferred l reduction (16 lanes of the quad)
#pragma unroll
    for (int r = 0; r < 4; ++r) {
#pragma unroll
        for (int off = 1; off < 16; off <<= 1)
            lsum[r] += __shfl_xor(lsum[r], off);
        lsum[r] = 1.0f / lsum[r];
    }

    // epilogue: bf16 ctx [b, s, h*64 + d]
#pragma unroll
    for (int t = 0; t < 4; ++t)
#pragma unroll
        for (int r = 0; r < 4; ++r) {
            const int row = qrow0 + r;
            ctx[((size_t)b * S_ + row) * D_ + (h << 6) + (t << 4) + lq] =
                f2bf(O[t][r] * lsum[r]);
        }
}

// ---------------------------------------------------------------------------
// Workspace layout (u16 units), ~61 MB total (unchanged):
//   [0)              xqb,xkb,xvb : 3*XBSZ  (bf16 X; dead after qkv_gemm)
//   [3*XBSZ)         wqb..wob    : 4*WBSZ  (bf16 W)
//   [3*XBSZ+4*WBSZ)  qw,kw,vw    : 3*QSZ
//   after that       mpk         : MPKB bytes (bit-packed mask)
//   cx aliases xqb (attn writes it after qkv_gemm's last read of xvb).
// ---------------------------------------------------------------------------
extern "C" void kernel_launch(void* const* d_in, const int* in_sizes, int n_in,
                              void* d_out, int out_size, void* d_ws, size_t ws_size,
                              hipStream_t stream)
{
    const float* Q    = (const float*)d_in[0];
    const float* K    = (const float*)d_in[1];
    const float* V    = (const float*)d_in[2];
    const int*   mask = (const int*)d_in[3];
    const float* Wq   = (const float*)d_in[4];
    const float* Wk   = (const float*)d_in[5];
    const float* Wv   = (const float*)d_in[6];
    const float* Wo   = (const float*)d_in[7];
    float* out = (float*)d_out;

    u16* xqb = (u16*)d_ws;
    u16* xkb = xqb + XBSZ;
    u16* xvb = xqb + 2 * XBSZ;
    u16* wqb = xqb + 3 * XBSZ;
    u16* wkb = wqb + WBSZ;
    u16* wvb = wqb + 2 * WBSZ;
    u16* wob = wqb + 3 * WBSZ;
    u16* qw  = wqb + 4 * WBSZ;
    u16* kw  = qw + QSZ;
    u16* vw  = qw + 2 * QSZ;
    u8*  mpk = (u8*)(qw + 3 * QSZ);
    u16* cx  = xqb;                 // alias: X-bf16 region is dead by then

    hipLaunchKernelGGL(cvt7m, dim3(2048), dim3(256), 0, stream,
                       Q, K, V, Wq, Wk, Wv, Wo, mask,
                       xqb, xkb, xvb, wqb, wkb, wvb, wob, mpk);
    hipLaunchKernelGGL(qkv_gemm, dim3(NROW / 128, D_ / 128, 3), dim3(256), 0, stream,
                       xqb, xkb, xvb, wqb, wkb, wvb, qw, kw, vw);
    hipLaunchKernelGGL(attn_mfma9, dim3(S_ / 128, H_, B_), dim3(512), 0, stream,
                       qw, kw, vw, mpk, cx);
    hipLaunchKernelGGL(out_gemm, dim3(NROW / 64, D_ / 64), dim3(256), 0, stream,
                       cx, wob, out);
}